// Round 1
// 338.674 us; speedup vs baseline: 1.0603x; 1.0603x over previous
//
#include <hip/hip_runtime.h>

// Problem constants
#define B_TOK 32768
#define D_IN  256
#define H1D   512
#define H2D   256
#define NE    16
#define NO    64
#define TK    128            // tokens per block

typedef _Float16 half8 __attribute__((ext_vector_type(8)));
typedef _Float16 half4 __attribute__((ext_vector_type(4)));
typedef float   float4_t __attribute__((ext_vector_type(4)));

// ---------------------------------------------------------------------------
// Prep kernel (grid 402 x 256), coalesced-read rewrite:
//  blocks 0..127   : W1 [E][D][H1] fp32 -> fragment-linear fp16 (LDS transpose)
//                    one block per (e, kt): 32x512 tile
//  blocks 128..383 : W2 [E][H1][H2] fp32 -> fragment-linear fp16 (LDS transpose)
//                    one block per (e, ktg): 32x256 tile
//  blocks 384..400 : w3h[e][h2] = W3[e][h2][:].head_w ; c3[e] = b3[e][:].head_w
//  block  401      : pack gate_w [D][E] -> 8 B-fragments
// Reads are float4-coalesced, writes are 1KB-contiguous per wave. The old
// version did 8 strided 4B gathers per thread straight from HBM.
// ---------------------------------------------------------------------------
__global__ void prep_kernel(const float* __restrict__ W1, const float* __restrict__ W2,
                            const float* __restrict__ W3, const float* __restrict__ b3,
                            const float* __restrict__ hw, const float* __restrict__ gw,
                            _Float16* __restrict__ w1p, _Float16* __restrict__ w2p,
                            float* __restrict__ w3h, float* __restrict__ c3,
                            _Float16* __restrict__ gwp) {
  // W1 tile: 32 rows x 512 cols, row stride 516 halves (1032 B: 8-row group
  // offset = 2064 dwords % 32 banks = 16 -> lane-groups split across 2 bank
  // halves, worst 4-way on 2B gather reads). 33,024 B.
  __shared__ _Float16 tile[32 * 516];
  const int blk = blockIdx.x;
  const int tid = threadIdx.x;

  if (blk < 128) {
    const int e = blk >> 3, kt = blk & 7;
    const float* src = W1 + ((size_t)(e * D_IN + kt * 32)) * H1D;
    #pragma unroll
    for (int it = 0; it < 16; ++it) {
      int idx = it * 256 + tid;               // 4096 float4s = 32x512
      int r = idx >> 7, c4 = idx & 127;
      float4_t v = *(const float4_t*)(src + (size_t)r * H1D + c4 * 4);
      half4 h;
      h[0] = (_Float16)v[0]; h[1] = (_Float16)v[1];
      h[2] = (_Float16)v[2]; h[3] = (_Float16)v[3];
      *(half4*)(tile + r * 516 + c4 * 4) = h;
    }
    __syncthreads();
    const int lane = tid & 63, wv = tid >> 6;
    #pragma unroll
    for (int it = 0; it < 8; ++it) {
      int ntg = it * 4 + wv;
      half8 v;
      #pragma unroll
      for (int j = 0; j < 8; ++j)
        v[j] = tile[((lane >> 4) * 8 + j) * 516 + ntg * 16 + (lane & 15)];
      *(half8*)(w1p + ((size_t)(((e * 32 + ntg) * 8 + kt) * 64 + lane)) * 8) = v;
    }
  } else if (blk < 384) {
    const int b2i = blk - 128;
    const int e = b2i >> 4, ktg = b2i & 15;
    const float* src = W2 + ((size_t)(e * H1D + ktg * 32)) * H2D;
    // 32 x 256 tile, row stride 260 halves (520 B; 8-row group offset
    // = 1040 dwords % 32 = 16 -> same 4-way worst case).
    #pragma unroll
    for (int it = 0; it < 8; ++it) {
      int idx = it * 256 + tid;               // 2048 float4s = 32x256
      int r = idx >> 6, c4 = idx & 63;
      float4_t v = *(const float4_t*)(src + (size_t)r * H2D + c4 * 4);
      half4 h;
      h[0] = (_Float16)v[0]; h[1] = (_Float16)v[1];
      h[2] = (_Float16)v[2]; h[3] = (_Float16)v[3];
      *(half4*)(tile + r * 260 + c4 * 4) = h;
    }
    __syncthreads();
    const int lane = tid & 63, wv = tid >> 6;
    #pragma unroll
    for (int it = 0; it < 4; ++it) {
      int ntg = it * 4 + wv;
      half8 v;
      #pragma unroll
      for (int j = 0; j < 8; ++j)
        v[j] = tile[((lane >> 4) * 8 + j) * 260 + ntg * 16 + (lane & 15)];
      *(half8*)(w2p + ((size_t)(((e * 16 + ntg) * 16 + ktg) * 64 + lane)) * 8) = v;
    }
  } else if (blk < 401) {
    int t = (blk - 384) * 256 + tid;
    if (t < NE * H2D) {
      int e = t >> 8, h = t & 255;
      float s = 0.f;
      #pragma unroll
      for (int o = 0; o < NO; ++o) s = fmaf(W3[((size_t)(e * H2D + h)) * NO + o], hw[o], s);
      w3h[t] = s;
    } else if (t < NE * H2D + NE) {
      int e = t - NE * H2D;
      float s = 0.f;
      #pragma unroll
      for (int o = 0; o < NO; ++o) s = fmaf(b3[e * NO + o], hw[o], s);
      c3[e] = s;
    }
  } else {
    for (int t = tid; t < 512; t += 256) {
      int lane = t & 63;
      int kt   = t >> 6;
      int e  = lane & 15;
      int kb = kt * 32 + (lane >> 4) * 8;
      half8 v;
      #pragma unroll
      for (int j = 0; j < 8; ++j)
        v[j] = (_Float16)gw[(kb + j) * NE + e];
      *(half8*)(gwp + (size_t)t * 8) = v;
    }
  }
}

// ---------------------------------------------------------------------------
// Fused main kernel. 256 blocks x 512 threads (8 waves, 2/SIMD), 128 tok/blk,
// 1 block/CU. x and h1 both fragment-linear in LDS (conflict-free layouts).
// Per expert, per 256-col chunk:
//   L1ch: wave w computes col-tiles {2w, 2w+1} x 8 token-tiles
//         (A=W1^T frags global, B=x frags LDS) -> frag-linear h1c -> barrier
//   L2ch: wave w computes h2col-tiles {2w, 2w+1} x 8 token-tiles
//         (A=h1c frags LDS, B=W2 frags global), accumulate -> barrier (WAR)
// New this round:
//  - s_setprio(1) around both MFMA kt-loops (T5: waves in MFMA phase win
//    scheduler arbitration over waves still in pack/epilogue).
//  - W2 fragment prefetch (kt 0..3, both j) issued AFTER the h1c pack
//    (a1[] dead -> no register-peak growth) and BEFORE the barrier, so the
//    L2 phase's first MFMAs don't stall on post-barrier vmcnt.
// Deferred-gate register epilogue; single shuffle-reduce at the end.
// ---------------------------------------------------------------------------
__global__ __launch_bounds__(512, 2) void moe_main(
    const float* __restrict__ x,
    const float* __restrict__ b1,
    const float* __restrict__ b2,
    const _Float16* __restrict__ w1p,
    const _Float16* __restrict__ w2p,
    const _Float16* __restrict__ gwp,
    const float* __restrict__ gb,
    const float* __restrict__ w3h,
    const float* __restrict__ c3,
    const float* __restrict__ head_b,
    float* __restrict__ out) {
  __shared__ _Float16 x_lds[64 * 512];             // 64 KB fragment-linear
  __shared__ _Float16 h1c[64 * 512];               // 64 KB fragment-linear chunk
  __shared__ float g_lds[TK * 17];                 // 8,704 B [token][e]
  __shared__ float fin[8 * TK];                    // 4 KB

  const int tid  = threadIdx.x;
  const int w    = tid >> 6;                       // 0..7
  const int lane = tid & 63;
  const int q    = lane >> 4;
  const int l16  = lane & 15;
  const int m0   = blockIdx.x * TK;

  // ---- stage x tile into LDS as MFMA A-fragments: frag (nt,kt) at
  //      x_lds[(nt*8+kt)*512 + lane*8]; wave w stages token tile w ----------
  #pragma unroll
  for (int f = 0; f < 8; ++f) {
    const float* xr = x + (size_t)(m0 + w * 16 + l16) * D_IN + f * 32 + q * 8;
    float4_t v0 = *(const float4_t*)(xr);
    float4_t v1 = *(const float4_t*)(xr + 4);
    half8 h;
    h[0] = (_Float16)v0[0]; h[1] = (_Float16)v0[1];
    h[2] = (_Float16)v0[2]; h[3] = (_Float16)v0[3];
    h[4] = (_Float16)v1[0]; h[5] = (_Float16)v1[1];
    h[6] = (_Float16)v1[2]; h[7] = (_Float16)v1[3];
    *(half8*)(x_lds + (size_t)(w * 8 + f) * 512 + lane * 8) = h;
  }
  __syncthreads();   // x_lds ready

  // ---- gates via MFMA + shuffle softmax; wave w handles token tile w ------
  {
    float gbv = gb[l16];
    float4_t lg = (float4_t){0.f, 0.f, 0.f, 0.f};
    #pragma unroll
    for (int kt = 0; kt < 8; ++kt) {
      half8 xa = *(const half8*)(x_lds + (size_t)(w * 8 + kt) * 512 + lane * 8);
      half8 bfr = *(const half8*)(gwp + (size_t)kt * 512 + lane * 8);
      lg = __builtin_amdgcn_mfma_f32_16x16x32_f16(xa, bfr, lg, 0, 0, 0);
    }
    #pragma unroll
    for (int r = 0; r < 4; ++r) {
      float v = lg[r] + gbv;                       // logit[token][e=l16]
      float m = v;
      m = fmaxf(m, __shfl_xor(m, 1));
      m = fmaxf(m, __shfl_xor(m, 2));
      m = fmaxf(m, __shfl_xor(m, 4));
      m = fmaxf(m, __shfl_xor(m, 8));
      float p = __expf(v - m);
      float s = p;
      s += __shfl_xor(s, 1);
      s += __shfl_xor(s, 2);
      s += __shfl_xor(s, 4);
      s += __shfl_xor(s, 8);
      g_lds[(w * 16 + q * 4 + r) * 17 + l16] = p / s;
    }
  }
  // g_lds becomes visible via in-loop barriers before first epilogue read.

  float yacc[8][4];    // gated accumulator: [mt][r] for token mt*16+q*4+r
  #pragma unroll
  for (int mt = 0; mt < 8; ++mt)
    #pragma unroll
    for (int r = 0; r < 4; ++r) yacc[mt][r] = 0.f;

  for (int e = 0; e < NE; ++e) {
    float4_t h2[8][2];   // [token tile][h2col tile j], accumulates over chunks
    #pragma unroll
    for (int mt = 0; mt < 8; ++mt)
      #pragma unroll
      for (int j = 0; j < 2; ++j)
        h2[mt][j] = (float4_t){0.f, 0.f, 0.f, 0.f};

    #pragma unroll
    for (int ch = 0; ch < 2; ++ch) {
      // ===== L1 chunk: wave w -> chunk col-tiles {2w, 2w+1} ================
      float4_t a1[2][8];   // [i = col tile][nt = token tile]
      #pragma unroll
      for (int i = 0; i < 2; ++i)
        #pragma unroll
        for (int nt = 0; nt < 8; ++nt)
          a1[i][nt] = (float4_t){0.f, 0.f, 0.f, 0.f};

      const _Float16* w1e =
          w1p + ((size_t)((e * 32 + ch * 16 + w * 2) * 8)) * 512 + lane * 8;
      __builtin_amdgcn_s_setprio(1);
      #pragma unroll
      for (int kt = 0; kt < 8; ++kt) {
        half8 wc[2];
        #pragma unroll
        for (int i = 0; i < 2; ++i)
          wc[i] = *(const half8*)(w1e + (size_t)(i * 8 + kt) * 512);
        half8 xb[8];
        #pragma unroll
        for (int nt = 0; nt < 8; ++nt)
          xb[nt] = *(const half8*)(x_lds + (size_t)(nt * 8 + kt) * 512 + lane * 8);
        #pragma unroll
        for (int i = 0; i < 2; ++i)
          #pragma unroll
          for (int nt = 0; nt < 8; ++nt)
            a1[i][nt] = __builtin_amdgcn_mfma_f32_16x16x32_f16(
                wc[i], xb[nt], a1[i][nt], 0, 0, 0);
      }
      __builtin_amdgcn_s_setprio(0);

      // bias + relu + store into FRAGMENT-LINEAR chunk layout.
      // a1[i][nt][r] = h1[tok = nt*16+l16][chunk col = (2w+i)*16 + q*4 + r].
      // chunk k-tile ktc = (2w+i)>>1 = w; lane' q' = 2i + (q>>1);
      // half-offset (q&1)*4 + r (consecutive). Verified vs A-operand reader.
      #pragma unroll
      for (int i = 0; i < 2; ++i) {
        int colbase = ch * 256 + (w * 2 + i) * 16 + q * 4;   // global h1 col
        float4_t bb = *(const float4_t*)(b1 + e * H1D + colbase);
        int qp = (i << 1) + (q >> 1);
        int fo = (qp * 16 + l16) * 8 + ((q & 1) << 2);
        #pragma unroll
        for (int nt = 0; nt < 8; ++nt) {
          half4 hv;
          #pragma unroll
          for (int r = 0; r < 4; ++r)
            hv[r] = (_Float16)fmaxf(a1[i][nt][r] + bb[r], 0.f);
          *(half4*)(h1c + (size_t)(nt * 8 + w) * 512 + fo) = hv;
        }
      }

      // ---- W2 fragment prefetch (a1 is dead here; +32 VGPRs in a low-
      //      pressure window). Loads fly across the barrier so L2's first
      //      MFMAs don't eat the full post-barrier vmcnt latency. ----------
      const _Float16* w2e =
          w2p + ((size_t)((e * 16 + w * 2) * 16 + ch * 8)) * 512 + lane * 8;
      half8 w2pre[2][4];
      #pragma unroll
      for (int j = 0; j < 2; ++j)
        #pragma unroll
        for (int kt = 0; kt < 4; ++kt)
          w2pre[j][kt] = *(const half8*)(w2e + (size_t)(j * 16 + kt) * 512);

      __syncthreads();   // h1 chunk ready

      // ===== L2 partial: wave w -> h2col-tiles {2w, 2w+1} ==================
      __builtin_amdgcn_s_setprio(1);
      #pragma unroll
      for (int kt = 0; kt < 8; ++kt) {
        half8 w2c[2];
        #pragma unroll
        for (int j = 0; j < 2; ++j)
          w2c[j] = (kt < 4) ? w2pre[j][kt]
                            : *(const half8*)(w2e + (size_t)(j * 16 + kt) * 512);
        half8 hac[8];
        #pragma unroll
        for (int mt = 0; mt < 8; ++mt)
          hac[mt] = *(const half8*)(h1c + (size_t)(mt * 8 + kt) * 512 + lane * 8);
        #pragma unroll
        for (int mt = 0; mt < 8; ++mt)
          #pragma unroll
          for (int j = 0; j < 2; ++j)
            h2[mt][j] = __builtin_amdgcn_mfma_f32_16x16x32_f16(
                hac[mt], w2c[j], h2[mt][j], 0, 0, 0);
      }
      __builtin_amdgcn_s_setprio(0);

      __syncthreads();   // WAR: h1c reads done before next chunk/expert L1
    }

    // ---- register epilogue: relu(h2+b2).w3h, gate folded, accumulate ------
    float b2v[2], w3v[2];
    #pragma unroll
    for (int j = 0; j < 2; ++j) {
      int n = (w * 2 + j) * 16 + l16;
      b2v[j] = b2[e * H2D + n];
      w3v[j] = w3h[e * H2D + n];
    }
    #pragma unroll
    for (int mt = 0; mt < 8; ++mt) {
      #pragma unroll
      for (int r = 0; r < 4; ++r) {
        float s = 0.f;
        #pragma unroll
        for (int j = 0; j < 2; ++j)
          s += fmaxf(h2[mt][j][r] + b2v[j], 0.f) * w3v[j];
        yacc[mt][r] += g_lds[(mt * 16 + q * 4 + r) * 17 + e] * s;
      }
    }
  }

  // ---- single final reduction: sum yacc over the 16 l16-lanes (cols) ------
  #pragma unroll
  for (int mt = 0; mt < 8; ++mt) {
    #pragma unroll
    for (int r = 0; r < 4; ++r) {
      float v = yacc[mt][r];
      v += __shfl_xor(v, 1);
      v += __shfl_xor(v, 2);
      v += __shfl_xor(v, 4);
      v += __shfl_xor(v, 8);
      yacc[mt][r] = v;
    }
  }
  if (l16 == 0) {
    #pragma unroll
    for (int mt = 0; mt < 8; ++mt)
      #pragma unroll
      for (int r = 0; r < 4; ++r)
        fin[w * TK + mt * 16 + q * 4 + r] = yacc[mt][r];
  }
  __syncthreads();
  if (tid < TK) {
    float sum = 0.f;
    #pragma unroll
    for (int k = 0; k < 8; ++k) sum += fin[k * TK + tid];
    float gc = 0.f;
    #pragma unroll
    for (int e = 0; e < NE; ++e) gc += g_lds[tid * 17 + e] * c3[e];
    out[m0 + tid] = sum + gc + head_b[0];
  }
}

// ---------------------------------------------------------------------------
extern "C" void kernel_launch(void* const* d_in, const int* in_sizes, int n_in,
                              void* d_out, int out_size, void* d_ws, size_t ws_size,
                              hipStream_t stream) {
  const float* x      = (const float*)d_in[0];
  const float* gate_w = (const float*)d_in[1];
  const float* gate_b = (const float*)d_in[2];
  const float* W1     = (const float*)d_in[3];
  const float* b1     = (const float*)d_in[4];
  const float* W2     = (const float*)d_in[5];
  const float* b2     = (const float*)d_in[6];
  const float* W3     = (const float*)d_in[7];
  const float* b3     = (const float*)d_in[8];
  const float* head_w = (const float*)d_in[9];
  const float* head_b = (const float*)d_in[10];
  float* out = (float*)d_out;

  // workspace layout (16B-aligned)
  char* ws = (char*)d_ws;
  _Float16* w1p = (_Float16*)(ws);                 // 4,194,304 B
  _Float16* w2p = (_Float16*)(ws + 4194304);       // 4,194,304 B
  _Float16* gwp = (_Float16*)(ws + 8388608);       // 8,192 B
  float*    w3h = (float*)(ws + 8396800);          // 16,384 B
  float*    c3  = (float*)(ws + 8413184);          // 64 B

  hipLaunchKernelGGL(prep_kernel, dim3(402), dim3(256), 0, stream,
                     W1, W2, W3, b3, head_w, gate_w, w1p, w2p, w3h, c3, gwp);
  hipLaunchKernelGGL(moe_main, dim3(B_TOK / TK), dim3(512), 0, stream,
                     x, b1, b2, w1p, w2p, gwp, gate_b, w3h, c3, head_b, out);
}